// Round 9
// baseline (260.388 us; speedup 1.0000x reference)
//
#include <hip/hip_runtime.h>
#include <cstdint>

#define B_  8
#define S_  2048
#define E_  1024
#define H_  128
#define NC_ 16          // chunks per sequence (S_/128)

typedef __attribute__((ext_vector_type(8))) short bf16x8;
typedef __attribute__((ext_vector_type(4))) float f32x4;

__device__ __forceinline__ short f2bf(float f){
  uint32_t u = __builtin_bit_cast(uint32_t, f);
  u = (u + 0x7fffu + ((u >> 16) & 1u)) >> 16;   // RNE
  return (short)u;
}
__device__ __forceinline__ float bf2f(short s){
  uint32_t u = ((uint32_t)(uint16_t)s) << 16;
  return __builtin_bit_cast(float, u);
}

// ---------------------------------------------------------------------------
// Kernel 1: W (E,H) f32 -> Wt (H,E) bf16, LDS-tiled transpose
// ---------------------------------------------------------------------------
__global__ __launch_bounds__(256) void wt_kernel(
    const float* __restrict__ WQ, const float* __restrict__ WK,
    const float* __restrict__ WV,
    short* __restrict__ WtQ, short* __restrict__ WtK, short* __restrict__ WtV)
{
  int which = blockIdx.z;
  const float* W = which == 0 ? WQ : which == 1 ? WK : WV;
  short* Wt      = which == 0 ? WtQ : which == 1 ? WtK : WtV;
  int k0 = blockIdx.x * 32, n0 = blockIdx.y * 32;
  __shared__ float t[32][33];
  int tx = threadIdx.x & 31, ty = threadIdx.x >> 5;
  #pragma unroll
  for (int i = 0; i < 4; i++)
    t[ty + i * 8][tx] = W[(size_t)(k0 + ty + i * 8) * H_ + n0 + tx];
  __syncthreads();
  #pragma unroll
  for (int i = 0; i < 4; i++)
    Wt[(size_t)(n0 + ty + i * 8) * E_ + k0 + tx] = f2bf(t[tx][ty + i * 8]);
}

// ---------------------------------------------------------------------------
// Kernel 2 v8: projections with COUNTED-VMCNT PIPELINE (T3/T4-lite + T14).
// Diagnosis r8: __syncthreads drains vmcnt(0) every chunk -> load pipe
// empty through every compute+barrier; all prior variants kept the drain
// (r1's dbuf) or lost LDS (r2/r7). Fix: raw s_barrier + writer-side
// lgkmcnt(0) ONLY — no vmcnt drain in the loop. Next chunk's A (regs) and
// B (BLOAD regs, BCOMMIT after compute) stay in flight across the barrier.
// 64-k chunks, dbuf LDS [2][128][72] = 36.9 KB -> 3 blocks/CU.
// Correctness: readers' ds_reads and writers' ds_writes both complete
// before each barrier via lgkmcnt(0); A-reg use gets compiler-inserted
// counted vmcnt (prefetched loads legally cross the raw barrier).
// ---------------------------------------------------------------------------
__global__ __launch_bounds__(256) void proj_kernel(
    const float* __restrict__ Xq, const float* __restrict__ Xk,
    const float* __restrict__ Xv,
    const short* __restrict__ Wtq, const short* __restrict__ Wtk,
    const short* __restrict__ Wtv,
    short* __restrict__ q, short* __restrict__ k,
    short* __restrict__ kT, short* __restrict__ vT)
{
  int which = blockIdx.y;
  const float* X  = which == 0 ? Xq  : which == 1 ? Xk  : Xv;
  const short* Wt = which == 0 ? Wtq : which == 1 ? Wtk : Wtv;

  int tid = threadIdx.x, lane = tid & 63, wave = tid >> 6;
  int lr = lane & 15, lq = lane >> 4;
  int rowbase = blockIdx.x * 64 + wave * 16;   // wave's 16 rows

  __shared__ short Bs[2][128 * 72];            // dbuf, padded stride 72

  const float* xr = X + (size_t)(rowbase + lr) * E_ + lq * 8;

  f32x4 acc[8];
  #pragma unroll
  for (int tn = 0; tn < 8; tn++) acc[tn] = (f32x4){0.f, 0.f, 0.f, 0.f};

  bf16x8 brA[4], brB[4];
  f32x4 a0[4], a1[4];

  auto BLOAD = [&](bf16x8* br, int t){
    #pragma unroll
    for (int v = 0; v < 4; v++){
      int c = v * 256 + tid;
      int n = c >> 3, off = (c & 7) * 8;
      br[v] = *(const bf16x8*)(Wt + (size_t)n * E_ + t * 64 + off);
    }
  };
  auto BCOMMIT = [&](int buf, const bf16x8* br){
    #pragma unroll
    for (int v = 0; v < 4; v++){
      int c = v * 256 + tid;
      int n = c >> 3, off = (c & 7) * 8;
      *(bf16x8*)(&Bs[buf][n * 72 + off]) = br[v];
    }
  };
  auto LOADA = [&](f32x4* a, int t){
    #pragma unroll
    for (int s = 0; s < 2; s++){
      a[2 * s]     = *(const f32x4*)(xr + t * 64 + s * 32);
      a[2 * s + 1] = *(const f32x4*)(xr + t * 64 + s * 32 + 4);
    }
  };
  auto COMPUTE = [&](int buf, const f32x4* ar){
    #pragma unroll
    for (int s = 0; s < 2; s++){
      bf16x8 a;
      #pragma unroll
      for (int j = 0; j < 4; j++){
        a[j] = f2bf(ar[2 * s][j]); a[4 + j] = f2bf(ar[2 * s + 1][j]);
      }
      #pragma unroll
      for (int tn = 0; tn < 8; tn++){
        bf16x8 bfr = *(const bf16x8*)(&Bs[buf][(tn * 16 + lr) * 72 + s * 32 + lq * 8]);
        acc[tn] = __builtin_amdgcn_mfma_f32_16x16x32_bf16(a, bfr, acc[tn], 0, 0, 0);
      }
    }
  };
  // writer lgkmcnt(0) then raw barrier — NO vmcnt drain
  #define SYNC_LDS() do { asm volatile("s_waitcnt lgkmcnt(0)" ::: "memory"); \
                          __builtin_amdgcn_s_barrier(); } while (0)

  // ---- prologue: chunk 0 into buf 0 ----
  BLOAD(brA, 0); LOADA(a0, 0);
  BCOMMIT(0, brA);
  SYNC_LDS();

  // ---- 16 chunks of 64-k, pairs keep reg-set indexing static ----
  for (int p = 0; p < 8; p++){
    int te = 2 * p;
    // even chunk te (buf 0): prefetch te+1 while computing
    BLOAD(brB, te + 1); LOADA(a1, te + 1);
    COMPUTE(0, a0);
    BCOMMIT(1, brB);
    SYNC_LDS();
    if (p < 7){
      // odd chunk te+1 (buf 1): prefetch te+2
      BLOAD(brA, te + 2); LOADA(a0, te + 2);
      COMPUTE(1, a1);
      BCOMMIT(0, brA);
      SYNC_LDS();
    } else {
      COMPUTE(1, a1);          // chunk 15, no prefetch
    }
  }
  #undef SYNC_LDS

  // ---- epilogue: C/D layout col=lane&15, row=(lane>>4)*4+reg ----
  if (which <= 1){
    short* P = which == 0 ? q : k;
    #pragma unroll
    for (int tn = 0; tn < 8; tn++)
      #pragma unroll
      for (int r4 = 0; r4 < 4; r4++)
        P[(size_t)(rowbase + lq * 4 + r4) * H_ + tn * 16 + lr] = f2bf(acc[tn][r4]);
  }
  if (which >= 1){
    short* T = which == 1 ? kT : vT;
    int b = rowbase >> 11, srow = rowbase & 2047;
    #pragma unroll
    for (int tn = 0; tn < 8; tn++){
      union { short sh[4]; uint2 u; } pk;
      #pragma unroll
      for (int r4 = 0; r4 < 4; r4++) pk.sh[r4] = f2bf(acc[tn][r4]);
      *(uint2*)(T + ((size_t)b * H_ + tn * 16 + lr) * S_ + srow + lq * 4) = pk.u;
    }
  }
}

// ---------------------------------------------------------------------------
// Kernel 3: fused chunk_state + exclusive prefix (r8, kept: ties r6 with
// one fewer launch). Prefix lives in the MFMA accumulator.
// ---------------------------------------------------------------------------
__global__ __launch_bounds__(256) void fused_state(
    const short* __restrict__ vT, const short* __restrict__ kT,
    short* __restrict__ Shi, short* __restrict__ Slo)
{
  int rh = blockIdx.x;            // h'-slice (32 rows of V-dim)
  int ch = blockIdx.y;            // h-half  (64 cols of K-dim)
  int b  = blockIdx.z;
  int tid = threadIdx.x, lane = tid & 63, wave = tid >> 6;
  int lr = lane & 15, lq = lane >> 4;

  __shared__ short As[2][32 * 136];   // vT slice rows (h' x t), 2x8.7 KB
  __shared__ short Bs[2][64 * 136];   // kT half rows (h x t),  2x17.4 KB

  const short* vtb = vT + (size_t)b * H_ * S_ + (size_t)(rh * 32) * S_;
  const short* ktb = kT + (size_t)b * H_ * S_ + (size_t)(ch * 64) * S_;

  f32x4 acc[2];
  acc[0] = (f32x4){0.f, 0.f, 0.f, 0.f};
  acc[1] = (f32x4){0.f, 0.f, 0.f, 0.f};

  for (int j = 0; j < NC_; j++){
    // ---- exclusive prefix for chunk j: acc -> Shi/Slo[j] ----
    size_t obase = (size_t)(b * NC_ + j) * 16384;
    #pragma unroll
    for (int tm = 0; tm < 2; tm++)
      #pragma unroll
      for (int r4 = 0; r4 < 4; r4++){
        int row = rh * 32 + tm * 16 + lq * 4 + r4;   // C/D: row=(lane>>4)*4+reg
        int col = ch * 64 + wave * 16 + lr;          //      col=lane&15
        float v = acc[tm][r4];
        short h = f2bf(v);
        Shi[obase + (size_t)row * 128 + col] = h;
        Slo[obase + (size_t)row * 128 + col] = f2bf(v - bf2f(h));
      }
    if (j == NC_ - 1) break;       // M_15 never needed

    // ---- stage chunk j tiles into buf = j&1 ----
    int buf = j & 1;
    #pragma unroll
    for (int v = 0; v < 2; v++){
      int c = v * 256 + tid;
      int r = c >> 4, off = (c & 15) * 8;
      *(bf16x8*)(&As[buf][r * 136 + off]) =
          *(const bf16x8*)(vtb + (size_t)r * S_ + j * 128 + off);
    }
    #pragma unroll
    for (int v = 0; v < 4; v++){
      int c = v * 256 + tid;
      int r = c >> 4, off = (c & 15) * 8;
      *(bf16x8*)(&Bs[buf][r * 136 + off]) =
          *(const bf16x8*)(ktb + (size_t)r * S_ + j * 128 + off);
    }
    __syncthreads();

    // ---- acc += M_j: 4 barrier-free t-steps ----
    #pragma unroll
    for (int s = 0; s < 4; s++){
      int t0 = s * 32;
      bf16x8 bfr = *(const bf16x8*)(&Bs[buf][(wave * 16 + lr) * 136 + t0 + lq * 8]);
      #pragma unroll
      for (int tm = 0; tm < 2; tm++){
        bf16x8 af = *(const bf16x8*)(&As[buf][(tm * 16 + lr) * 136 + t0 + lq * 8]);
        acc[tm] = __builtin_amdgcn_mfma_f32_16x16x32_bf16(af, bfr, acc[tm], 0, 0, 0);
      }
    }
  }
}

// ---------------------------------------------------------------------------
// Kernel 4: per (b, chunk i, row-QUARTER): 32 rows of
//   O = (Q_i K_i^T . tril) V_i + Q_i (State_hi + State_lo)
// r3 verbatim. All global tile loads issued at kernel entry (T14). 4 barriers.
// ---------------------------------------------------------------------------
__global__ __launch_bounds__(256) void passC(
    const short* __restrict__ qb, const short* __restrict__ kb,
    const short* __restrict__ vT, const short* __restrict__ Shi,
    const short* __restrict__ Slo, float* __restrict__ out)
{
  int i = blockIdx.x, qtr = blockIdx.y, b = blockIdx.z;
  int roff = qtr * 32;
  int tid = threadIdx.x, lane = tid & 63, wave = tid >> 6;
  int wcol = wave * 32;
  int lr = lane & 15, lq = lane >> 4;

  __shared__ short Ss[32 * 136];    // masked scores (8.7 KB)
  __shared__ short Bt0[128 * 136];  // K, then Shi  (34.8 KB)
  __shared__ short Bt1[128 * 136];  // V, then Slo  (34.8 KB)

  const short* qbase = qb + ((size_t)b * S_ + i * 128 + roff) * H_;
  const short* kbase = kb + ((size_t)b * S_ + i * 128) * H_;
  const short* vtb   = vT + (size_t)b * H_ * S_ + i * 128;
  const short* shib  = Shi + (size_t)(b * NC_ + i) * 16384;
  const short* slob  = Slo + (size_t)(b * NC_ + i) * 16384;

  // ---- issue ALL global loads up front: 40 x 16B per lane in flight ----
  bf16x8 kst[8], vst[8], hst[8], lst[8];
  #pragma unroll
  for (int v = 0; v < 8; v++){
    int c = v * 256 + tid;
    int r = c >> 4, off = (c & 15) * 8;
    kst[v] = *(const bf16x8*)(kbase + (size_t)r * H_ + off);
    vst[v] = *(const bf16x8*)(vtb  + (size_t)r * S_ + off);
    hst[v] = *(const bf16x8*)(shib + (size_t)r * 128 + off);
    lst[v] = *(const bf16x8*)(slob + (size_t)r * 128 + off);
  }
  bf16x8 aq[2][4];   // Q rows tm*16+lr (32 rows of this quarter)
  #pragma unroll
  for (int tm = 0; tm < 2; tm++)
    #pragma unroll
    for (int hs = 0; hs < 4; hs++)
      aq[tm][hs] = *(const bf16x8*)(
          qbase + (size_t)(tm * 16 + lr) * H_ + hs * 32 + lq * 8);

  // K -> Bt0
  #pragma unroll
  for (int v = 0; v < 8; v++){
    int c = v * 256 + tid;
    int r = c >> 4, off = (c & 15) * 8;
    *(bf16x8*)(&Bt0[r * 136 + off]) = kst[v];
  }
  __syncthreads();                           // barrier 1

  f32x4 accS[2][2];
  #pragma unroll
  for (int a = 0; a < 2; a++)
    #pragma unroll
    for (int c = 0; c < 2; c++) accS[a][c] = (f32x4){0.f, 0.f, 0.f, 0.f};

  // ---- phase 1: S = Q K^T, wave's t-slice = wcol..wcol+31 ----
  #pragma unroll
  for (int hs = 0; hs < 4; hs++){
    bf16x8 bf[2];
    #pragma unroll
    for (int tn = 0; tn < 2; tn++)
      bf[tn] = *(const bf16x8*)(&Bt0[(wcol + tn * 16 + lr) * 136 + hs * 32 + lq * 8]);
    #pragma unroll
    for (int tm = 0; tm < 2; tm++)
      #pragma unroll
      for (int tn = 0; tn < 2; tn++)
        accS[tm][tn] = __builtin_amdgcn_mfma_f32_16x16x32_bf16(
            aq[tm][hs], bf[tn], accS[tm][tn], 0, 0, 0);
  }

  // ---- phase 2: mask + bf16 -> Ss; land V -> Bt1 ----
  #pragma unroll
  for (int tm = 0; tm < 2; tm++)
    #pragma unroll
    for (int tn = 0; tn < 2; tn++)
      #pragma unroll
      for (int r4 = 0; r4 < 4; r4++){
        int row = tm * 16 + lq * 4 + r4;            // local row 0..31
        int col = wcol + tn * 16 + lr;              // t index 0..127
        float vv = (col <= roff + row) ? accS[tm][tn][r4] : 0.f;
        Ss[row * 136 + col] = f2bf(vv);
      }
  #pragma unroll
  for (int v = 0; v < 8; v++){
    int c = v * 256 + tid;
    int r = c >> 4, off = (c & 15) * 8;
    *(bf16x8*)(&Bt1[r * 136 + off]) = vst[v];
  }
  f32x4 acc[2][2];
  #pragma unroll
  for (int a = 0; a < 2; a++)
    #pragma unroll
    for (int c = 0; c < 2; c++) acc[a][c] = (f32x4){0.f, 0.f, 0.f, 0.f};
  __syncthreads();                           // barrier 2

  // ---- phase 3a: O += S V, wave's h'-slice = wcol; land Shi -> Bt0 ----
  #pragma unroll
  for (int s = 0; s < 4; s++){
    int t0 = s * 32;
    bf16x8 af[2], bf[2];
    #pragma unroll
    for (int tm = 0; tm < 2; tm++)
      af[tm] = *(const bf16x8*)(&Ss[(tm * 16 + lr) * 136 + t0 + lq * 8]);
    #pragma unroll
    for (int tn = 0; tn < 2; tn++)
      bf[tn] = *(const bf16x8*)(&Bt1[(wcol + tn * 16 + lr) * 136 + t0 + lq * 8]);
    #pragma unroll
    for (int tm = 0; tm < 2; tm++)
      #pragma unroll
      for (int tn = 0; tn < 2; tn++)
        acc[tm][tn] = __builtin_amdgcn_mfma_f32_16x16x32_bf16(
            af[tm], bf[tn], acc[tm][tn], 0, 0, 0);
  }
  #pragma unroll
  for (int v = 0; v < 8; v++){
    int c = v * 256 + tid;
    int r = c >> 4, off = (c & 15) * 8;
    *(bf16x8*)(&Bt0[r * 136 + off]) = hst[v];
  }
  __syncthreads();                           // barrier 3

  // ---- phase 3b-hi: O += Q * State_hi (Bt0); land Slo -> Bt1 ----
  #pragma unroll
  for (int hs = 0; hs < 4; hs++){
    bf16x8 bf[2];
    #pragma unroll
    for (int tn = 0; tn < 2; tn++)
      bf[tn] = *(const bf16x8*)(&Bt0[(wcol + tn * 16 + lr) * 136 + hs * 32 + lq * 8]);
    #pragma unroll
    for (int tm = 0; tm < 2; tm++)
      #pragma unroll
      for (int tn = 0; tn < 2; tn++)
        acc[tm][tn] = __builtin_amdgcn_mfma_f32_16x16x32_bf16(
            aq[tm][hs], bf[tn], acc[tm][tn], 0, 0, 0);
  }
  #pragma unroll
  for (int v = 0; v < 8; v++){
    int c = v * 256 + tid;
    int r = c >> 4, off = (c & 15) * 8;
    *(bf16x8*)(&Bt1[r * 136 + off]) = lst[v];
  }
  __syncthreads();                           // barrier 4

  // ---- phase 3b-lo: O += Q * State_lo (Bt1) ----
  #pragma unroll
  for (int hs = 0; hs < 4; hs++){
    bf16x8 bf[2];
    #pragma unroll
    for (int tn = 0; tn < 2; tn++)
      bf[tn] = *(const bf16x8*)(&Bt1[(wcol + tn * 16 + lr) * 136 + hs * 32 + lq * 8]);
    #pragma unroll
    for (int tm = 0; tm < 2; tm++)
      #pragma unroll
      for (int tn = 0; tn < 2; tn++)
        acc[tm][tn] = __builtin_amdgcn_mfma_f32_16x16x32_bf16(
            aq[tm][hs], bf[tn], acc[tm][tn], 0, 0, 0);
  }

  // ---- epilogue ----
  float* ob = out + ((size_t)b * S_ + i * 128 + roff) * H_;
  #pragma unroll
  for (int tm = 0; tm < 2; tm++)
    #pragma unroll
    for (int tn = 0; tn < 2; tn++)
      #pragma unroll
      for (int r4 = 0; r4 < 4; r4++){
        int row = tm * 16 + lq * 4 + r4;
        int col = wcol + tn * 16 + lr;
        ob[(size_t)row * H_ + col] = acc[tm][tn][r4];
      }
}

// ---------------------------------------------------------------------------
extern "C" void kernel_launch(void* const* d_in, const int* in_sizes, int n_in,
                              void* d_out, int out_size, void* d_ws, size_t ws_size,
                              hipStream_t stream) {
  // setup_inputs order: key, query, value, W_Q, W_K, W_V (all fp32)
  const float* key   = (const float*)d_in[0];
  const float* query = (const float*)d_in[1];
  const float* value = (const float*)d_in[2];
  const float* WQ    = (const float*)d_in[3];
  const float* WK    = (const float*)d_in[4];
  const float* WV    = (const float*)d_in[5];
  float* out = (float*)d_out;

  char* w = (char*)d_ws;
  short* WtQ = (short*)(w + 0);                       // 3 x 256 KB
  short* WtK = (short*)(w + 262144);
  short* WtV = (short*)(w + 524288);
  size_t o = 786432;
  short* q  = (short*)(w + o); o += 4194304;          // (B,S,H) bf16
  short* k  = (short*)(w + o); o += 4194304;
  short* kT = (short*)(w + o); o += 4194304;          // (B,H,S) bf16
  short* vT = (short*)(w + o); o += 4194304;
  short* Shi= (short*)(w + o); o += 4194304;          // exclusive prefix, bf16 hi
  short* Slo= (short*)(w + o); o += 4194304;          // bf16 residual

  wt_kernel   <<<dim3(32, 4, 3),       256, 0, stream>>>(WQ, WK, WV, WtQ, WtK, WtV);
  proj_kernel <<<dim3(256, 3),         256, 0, stream>>>(query, key, value,
                                                         WtQ, WtK, WtV, q, k, kT, vT);
  fused_state <<<dim3(4, 2, B_),       256, 0, stream>>>(vT, kT, Shi, Slo);
  passC       <<<dim3(NC_, 4, B_),     256, 0, stream>>>(q, k, vT, Shi, Slo, out);
}